// Round 4
// baseline (486.519 us; speedup 1.0000x reference)
//
#include <hip/hip_runtime.h>
#include <hip/hip_bf16.h>

typedef __attribute__((ext_vector_type(8))) short v8s;   // 8 x bf16 (4 VGPRs)
typedef __attribute__((ext_vector_type(4))) float v4f;   // MFMA accum

#define GL16(g, l) __builtin_amdgcn_global_load_lds(                    \
    (const __attribute__((address_space(1))) void*)(g),                 \
    (__attribute__((address_space(3))) void*)(l), 16, 0, 0)

static constexpr int BB = 2, SS = 2048, HIDC = 2048, NH = 16, NKV = 4, DD = 128;
static constexpr int MM = BB * SS;        // 4096 rows
static constexpr int LDQKV = 3072;        // q(2048) | k(512) | v(512)
static constexpr int NCHUNK = 32;         // S / SPLIT
static constexpr int NCG = 2;             // chunk groups (parallel split)
static constexpr int CPG = NCHUNK / NCG;  // chunks per group = 16
#define SCALE_F 0.08838834764831845f

__device__ __forceinline__ unsigned short bf16b(float x) {
  unsigned u = __float_as_uint(x);
  u += 0x7fffu + ((u >> 16) & 1u);        // RTNE
  return (unsigned short)(u >> 16);
}
__device__ __forceinline__ unsigned pk2(float lo, float hi) {
  return (unsigned)bf16b(lo) | ((unsigned)bf16b(hi) << 16);
}
__device__ __forceinline__ float bf2f(unsigned short u) {
  return __uint_as_float((unsigned)u << 16);
}

// ---------------- fp32 -> bf16 cast ----------------
__global__ __launch_bounds__(256) void cast_kernel(
    const float* __restrict__ in, unsigned short* __restrict__ out, int n4) {
  int i = blockIdx.x * blockDim.x + threadIdx.x;
  if (i >= n4) return;
  v4f v = reinterpret_cast<const v4f*>(in)[i];
  ushort4 o;
  o.x = bf16b(v[0]); o.y = bf16b(v[1]); o.z = bf16b(v[2]); o.w = bf16b(v[3]);
  reinterpret_cast<ushort4*>(out)[i] = o;
}

// ---------------- NT GEMM, m97 structure: 128x128 tile, BK=32 ----------------
// C[m][n] = sum_k A[m][k] * B[n][k].  MODE 0: fused QKV -> bf16 qkv buffer
// (ldc=3072, weight selected per n-block). MODE 1: fp32 C (out projection).
template <int MODE>
__global__ __launch_bounds__(256) void gemm_bt(
    const unsigned short* __restrict__ A, const unsigned short* __restrict__ W0,
    const unsigned short* __restrict__ W1, const unsigned short* __restrict__ W2,
    void* __restrict__ Cout) {
  __shared__ __align__(16) unsigned short As[128 * 32];
  __shared__ __align__(16) unsigned short Bs[128 * 32];
  const int K = HIDC;
  int mb = blockIdx.x, nb = blockIdx.y;
  int tid = threadIdx.x, wid = tid >> 6, lane = tid & 63;
  int l15 = lane & 15, g = lane >> 4;
  const unsigned short* Bsel;
  int nloc0, ldc;
  if (MODE == 0) {
    if (nb < 16)      { Bsel = W0; nloc0 = nb * 128; }
    else if (nb < 20) { Bsel = W1; nloc0 = (nb - 16) * 128; }
    else              { Bsel = W2; nloc0 = (nb - 20) * 128; }
    ldc = LDQKV;
  } else {
    Bsel = W0; nloc0 = nb * 128; ldc = 2048;
  }
  int wr = wid >> 1, wc = wid & 1;
  v4f acc[4][4] = {};

  for (int kt = 0; kt < K / 32; ++kt) {
    // stage A,B tiles: 512 chunks of 16B each; swizzle chunk' = chunk ^ ((row>>1)&3)
#pragma unroll
    for (int i = 0; i < 2; ++i) {
      int ci = (i * 4 + wid) * 64 + lane;          // 0..511
      int row = ci >> 2, ch = ci & 3;
      int cg = ch ^ ((row >> 1) & 3);
      const unsigned short* ga = A + (size_t)(mb * 128 + row) * K + kt * 32 + cg * 8;
      GL16(ga, (char*)As + (size_t)(i * 4 + wid) * 1024);
      const unsigned short* gb = Bsel + (size_t)(nloc0 + row) * K + kt * 32 + cg * 8;
      GL16(gb, (char*)Bs + (size_t)(i * 4 + wid) * 1024);
    }
    __syncthreads();
    v8s af[4], bfr[4];
#pragma unroll
    for (int mi = 0; mi < 4; ++mi) {
      int row = wr * 64 + mi * 16 + l15;
      int ch = g ^ ((row >> 1) & 3);
      af[mi] = *reinterpret_cast<const v8s*>(&As[row * 32 + ch * 8]);
    }
#pragma unroll
    for (int ni = 0; ni < 4; ++ni) {
      int row = wc * 64 + ni * 16 + l15;
      int ch = g ^ ((row >> 1) & 3);
      bfr[ni] = *reinterpret_cast<const v8s*>(&Bs[row * 32 + ch * 8]);
    }
#pragma unroll
    for (int mi = 0; mi < 4; ++mi)
#pragma unroll
      for (int ni = 0; ni < 4; ++ni)
        acc[mi][ni] = __builtin_amdgcn_mfma_f32_16x16x32_bf16(
            af[mi], bfr[ni], acc[mi][ni], 0, 0, 0);
    __syncthreads();
  }

  // epilogue: C/D layout col = lane&15, row = (lane>>4)*4 + i
  int cbase = nb * 128;
  if (MODE == 0) {
    unsigned short* C = (unsigned short*)Cout;
#pragma unroll
    for (int mi = 0; mi < 4; ++mi)
#pragma unroll
      for (int ni = 0; ni < 4; ++ni)
#pragma unroll
        for (int i = 0; i < 4; ++i) {
          int r = mb * 128 + wr * 64 + mi * 16 + g * 4 + i;
          int cc = cbase + wc * 64 + ni * 16 + l15;
          C[(size_t)r * ldc + cc] = bf16b(acc[mi][ni][i]);
        }
  } else {
    float* C = (float*)Cout;
#pragma unroll
    for (int mi = 0; mi < 4; ++mi)
#pragma unroll
      for (int ni = 0; ni < 4; ++ni)
#pragma unroll
        for (int i = 0; i < 4; ++i) {
          int r = mb * 128 + wr * 64 + mi * 16 + g * 4 + i;
          int cc = cbase + wc * 64 + ni * 16 + l15;
          C[(size_t)r * ldc + cc] = acc[mi][ni][i];
        }
  }
}

// ---------------- V transpose: qkv v-cols -> VT[b][kh][d][s] ----------------
__global__ __launch_bounds__(256) void transpose_v(
    const unsigned short* __restrict__ qkv, unsigned short* __restrict__ VT) {
  __shared__ __align__(16) unsigned short t_lds[64 * 72];
  int blk = blockIdx.x;              // 512 = 2b * 4kh * 2dt * 32st
  int st = blk & 31;
  int dt = (blk >> 5) & 1;
  int bkh = blk >> 6;                // b*4 + kh
  int b = bkh >> 2, kh = bkh & 3;
  int tid = threadIdx.x;
  int si = tid >> 2, c8 = (tid & 3) * 16;
  const unsigned short* src =
      qkv + (size_t)(b * SS + st * 64 + si) * LDQKV + 2560 + kh * 128 + dt * 64 + c8;
  *reinterpret_cast<v8s*>(&t_lds[si * 72 + c8]) = *reinterpret_cast<const v8s*>(src);
  *reinterpret_cast<v8s*>(&t_lds[si * 72 + c8 + 8]) = *reinterpret_cast<const v8s*>(src + 8);
  __syncthreads();
  int dl = tid >> 2, s0 = (tid & 3) * 16;
  union { unsigned short u[16]; v8s v[2]; } tt;
#pragma unroll
  for (int j = 0; j < 16; ++j) tt.u[j] = t_lds[(s0 + j) * 72 + dl];
  unsigned short* dst = VT + (size_t)(bkh * 128 + dt * 64 + dl) * SS + st * 64 + s0;
  *reinterpret_cast<v8s*>(dst) = tt.v[0];
  *reinterpret_cast<v8s*>(dst + 8) = tt.v[1];
}

// ---------------- fused chunked attention (chunk-group split) ----------------
// Grid 1024: logical = b(1)|h(4)|qt(4)|cg(1). 4 waves x 32 q-rows. Swapped QK^T:
// S^T[key][q] = mfma(K_frag, Q^T_frag). Chunk-local softmax (no running max).
// O^T[d][q] accumulated over CPG chunks; raw bf16 partial -> part0 or part1.
__global__ __launch_bounds__(256) void attn_kernel(
    const unsigned short* __restrict__ qkv, const unsigned short* __restrict__ VT,
    const float* __restrict__ mask, unsigned short* __restrict__ part0,
    unsigned short* __restrict__ part1) {
  __shared__ __align__(16) unsigned short K_lds[64 * 128];   // [key][d] swizzled
  __shared__ __align__(16) unsigned short V_lds[128 * 64];   // [d][key] swizzled
  int wg = blockIdx.x;
  int logical = (wg & 7) * 128 + (wg >> 3);   // contiguous 128-chunk per XCD
  int cg = logical & 1;
  int qt = (logical >> 1) & 15;
  int h = (logical >> 5) & 15;
  int b = logical >> 9;
  int kh = h >> 2;
  int tid = threadIdx.x, wid = tid >> 6, lane = tid & 63;
  int l15 = lane & 15, g = lane >> 4;
  int qr0 = qt * 128 + wid * 32;

  // Q fragments in registers: B-operand of swapped QK^T (Q rows, K-contig)
  v8s qf[2][4];
#pragma unroll
  for (int nf = 0; nf < 2; ++nf)
#pragma unroll
    for (int ks = 0; ks < 4; ++ks) {
      const unsigned short* src =
          qkv + (size_t)(b * SS + qr0 + nf * 16 + l15) * LDQKV + h * 128 + ks * 32 + g * 8;
      qf[nf][ks] = *reinterpret_cast<const v8s*>(src);
    }

  v4f oacc[8][2] = {};   // O^T: [d-frag][q-frag]

  const size_t krowbase = (size_t)b * SS * LDQKV + 2048 + kh * 128;
  const unsigned short* vtbase = VT + (size_t)(b * 4 + kh) * 128 * SS;

  for (int c = cg * CPG; c < cg * CPG + CPG; ++c) {
    // stage K (64x128, 16 chunks/row) and VT (128x64, 8 chunks/row),
    // source pre-swizzled: stored chunk' holds global chunk (chunk' ^ (row&7))
#pragma unroll
    for (int i = 0; i < 4; ++i) {
      int ci = (i * 4 + wid) * 64 + lane;    // 0..1023
      {
        int row = ci >> 4, ch = ci & 15;
        int cgx = ch ^ (row & 7);
        const unsigned short* gk = qkv + krowbase + (size_t)(c * 64 + row) * LDQKV + cgx * 8;
        GL16(gk, (char*)K_lds + (size_t)(i * 4 + wid) * 1024);
      }
      {
        int row = ci >> 3, ch = ci & 7;
        int cgx = ch ^ (row & 7);
        const unsigned short* gv = vtbase + (size_t)row * SS + c * 64 + cgx * 8;
        GL16(gv, (char*)V_lds + (size_t)(i * 4 + wid) * 1024);
      }
    }
    __syncthreads();

    // S^T = K * Q^T  (M=64 keys, N=32 q, K-dim = 128 d)
    v4f sc[4][2] = {};
#pragma unroll
    for (int ks = 0; ks < 4; ++ks) {
      v8s kf[4];
#pragma unroll
      for (int mf = 0; mf < 4; ++mf) {
        int row = mf * 16 + l15;
        int ch = (4 * ks + g) ^ (row & 7);
        kf[mf] = *reinterpret_cast<const v8s*>(&K_lds[row * 128 + ch * 8]);
      }
#pragma unroll
      for (int mf = 0; mf < 4; ++mf)
#pragma unroll
        for (int nf = 0; nf < 2; ++nf)
          sc[mf][nf] = __builtin_amdgcn_mfma_f32_16x16x32_bf16(
              kf[mf], qf[nf][ks], sc[mf][nf], 0, 0, 0);
    }

    // scale + mask: value(key = c*64 + mf*16 + g*4 + i, q = qr0 + nf*16 + l15)
#pragma unroll
    for (int mf = 0; mf < 4; ++mf)
#pragma unroll
      for (int nf = 0; nf < 2; ++nf) {
        int q = qr0 + nf * 16 + l15;
        v4f mv = *reinterpret_cast<const v4f*>(
            mask + (size_t)(b * SS + q) * SS + c * 64 + mf * 16 + g * 4);
#pragma unroll
        for (int i = 0; i < 4; ++i)
          sc[mf][nf][i] = sc[mf][nf][i] * SCALE_F + mv[i];
      }

    // chunk-local softmax over 64 keys per q (in-lane 16 + shfl_xor 16,32)
    unsigned wA[4][2], wB[4][2];
#pragma unroll
    for (int nf = 0; nf < 2; ++nf) {
      float m = -1e30f;
#pragma unroll
      for (int mf = 0; mf < 4; ++mf)
#pragma unroll
        for (int i = 0; i < 4; ++i) m = fmaxf(m, sc[mf][nf][i]);
      m = fmaxf(m, __shfl_xor(m, 16));
      m = fmaxf(m, __shfl_xor(m, 32));
      float s = 0.f;
#pragma unroll
      for (int mf = 0; mf < 4; ++mf)
#pragma unroll
        for (int i = 0; i < 4; ++i) {
          float p = __expf(sc[mf][nf][i] - m);
          sc[mf][nf][i] = p;
          s += p;
        }
      s += __shfl_xor(s, 16);
      s += __shfl_xor(s, 32);
      float r = 1.f / s;
#pragma unroll
      for (int mf = 0; mf < 4; ++mf) {
        wA[mf][nf] = pk2(sc[mf][nf][0] * r, sc[mf][nf][1] * r);
        wB[mf][nf] = pk2(sc[mf][nf][2] * r, sc[mf][nf][3] * r);
      }
    }

    // O^T += V^T * P^T : build P^T B-frags in-register (group shuffles)
    int src0 = ((lane >> 4) & 1) * 32 + l15;
    int src1 = src0 + 16;
    bool hi = lane >= 32;    // selects frag m = 2t + (g>>1)
#pragma unroll
    for (int t = 0; t < 2; ++t) {
      v8s vf[8];
#pragma unroll
      for (int mf = 0; mf < 8; ++mf) {
        int row = mf * 16 + l15;
        int ch = (4 * t + g) ^ (row & 7);
        vf[mf] = *reinterpret_cast<const v8s*>(&V_lds[row * 64 + ch * 8]);
      }
#pragma unroll
      for (int nf = 0; nf < 2; ++nf) {
        int m0 = 2 * t, m1 = 2 * t + 1;
        unsigned aA0 = __shfl(wA[m0][nf], src0);
        unsigned aA1 = __shfl(wA[m1][nf], src0);
        unsigned aB0 = __shfl(wB[m0][nf], src0);
        unsigned aB1 = __shfl(wB[m1][nf], src0);
        unsigned cA0 = __shfl(wA[m0][nf], src1);
        unsigned cA1 = __shfl(wA[m1][nf], src1);
        unsigned cB0 = __shfl(wB[m0][nf], src1);
        unsigned cB1 = __shfl(wB[m1][nf], src1);
        union { unsigned u[4]; v8s s; } pb;
        pb.u[0] = hi ? aA1 : aA0;
        pb.u[1] = hi ? aB1 : aB0;
        pb.u[2] = hi ? cA1 : cA0;
        pb.u[3] = hi ? cB1 : cB0;
#pragma unroll
        for (int mf = 0; mf < 8; ++mf)
          oacc[mf][nf] = __builtin_amdgcn_mfma_f32_16x16x32_bf16(
              vf[mf], pb.s, oacc[mf][nf], 0, 0, 0);
      }
    }
    __syncthreads();
  }

  // epilogue: raw partial sum (no /32 here), bf16 -> part0 (cg=0) or part1 (cg=1)
  unsigned short* pslab = cg ? part1 : part0;
#pragma unroll
  for (int nf = 0; nf < 2; ++nf) {
    int q = qr0 + nf * 16 + l15;
#pragma unroll
    for (int mf = 0; mf < 8; ++mf) {
      ushort4 o;
      o.x = bf16b(oacc[mf][nf][0]);
      o.y = bf16b(oacc[mf][nf][1]);
      o.z = bf16b(oacc[mf][nf][2]);
      o.w = bf16b(oacc[mf][nf][3]);
      *reinterpret_cast<ushort4*>(
          pslab + (size_t)(b * SS + q) * 2048 + h * 128 + mf * 16 + g * 4) = o;
    }
  }
}

// ---------------- partial reduce (in place): p0 = (p0 + p1) / 32 ----------------
__global__ __launch_bounds__(256) void reduce_kernel(
    unsigned short* __restrict__ p0, const unsigned short* __restrict__ p1, int n8) {
  int i = blockIdx.x * blockDim.x + threadIdx.x;
  if (i >= n8) return;
  v8s a = reinterpret_cast<const v8s*>(p0)[i];
  v8s bb = reinterpret_cast<const v8s*>(p1)[i];
  const float inv = 1.f / 32.f;
  union { unsigned short u[8]; v8s v; } o;
#pragma unroll
  for (int j = 0; j < 8; ++j)
    o.u[j] = bf16b((bf2f((unsigned short)a[j]) + bf2f((unsigned short)bb[j])) * inv);
  reinterpret_cast<v8s*>(p0)[i] = o.v;
}

// ---------------- host ----------------
extern "C" void kernel_launch(void* const* d_in, const int* in_sizes, int n_in,
                              void* d_out, int out_size, void* d_ws, size_t ws_size,
                              hipStream_t stream) {
  const float* hs   = (const float*)d_in[0];
  const float* mask = (const float*)d_in[1];
  const float* Wq   = (const float*)d_in[2];
  const float* Wk   = (const float*)d_in[3];
  const float* Wv   = (const float*)d_in[4];
  const float* Wo   = (const float*)d_in[5];

  char* ws = (char*)d_ws;
  size_t off = 0;
  auto alloc = [&](size_t bytes) {
    void* p = ws + off;
    off += (bytes + 255) & ~(size_t)255;
    return p;
  };
  // Buffer plan (84 MB total — identical footprint to the known-good round 1):
  //   hs_b: QKV-GEMM input A; DEAD after gemm<0> -> reused as partial slab 1.
  //   attb: partial slab 0, reduced in place, then out-GEMM input A.
  unsigned short* hs_b = (unsigned short*)alloc((size_t)MM * HIDC * 2);
  unsigned short* Wq_b = (unsigned short*)alloc((size_t)2048 * 2048 * 2);
  unsigned short* Wk_b = (unsigned short*)alloc((size_t)512 * 2048 * 2);
  unsigned short* Wv_b = (unsigned short*)alloc((size_t)512 * 2048 * 2);
  unsigned short* Wo_b = (unsigned short*)alloc((size_t)2048 * 2048 * 2);
  unsigned short* qkvb = (unsigned short*)alloc((size_t)MM * LDQKV * 2);
  unsigned short* VTb  = (unsigned short*)alloc((size_t)8 * 128 * SS * 2);
  unsigned short* attb = (unsigned short*)alloc((size_t)MM * 2048 * 2);
  (void)ws_size; (void)in_sizes; (void)n_in; (void)out_size;

  cast_kernel<<<MM * HIDC / 1024, 256, 0, stream>>>(hs, hs_b, MM * HIDC / 4);
  cast_kernel<<<2048 * 2048 / 1024, 256, 0, stream>>>(Wq, Wq_b, 2048 * 2048 / 4);
  cast_kernel<<<512 * 2048 / 1024, 256, 0, stream>>>(Wk, Wk_b, 512 * 2048 / 4);
  cast_kernel<<<512 * 2048 / 1024, 256, 0, stream>>>(Wv, Wv_b, 512 * 2048 / 4);
  cast_kernel<<<2048 * 2048 / 1024, 256, 0, stream>>>(Wo, Wo_b, 2048 * 2048 / 4);

  gemm_bt<0><<<dim3(32, 24), 256, 0, stream>>>(hs_b, Wq_b, Wk_b, Wv_b, (void*)qkvb);
  transpose_v<<<512, 256, 0, stream>>>(qkvb, VTb);
  attn_kernel<<<1024, 256, 0, stream>>>(qkvb, VTb, mask, attb, hs_b);
  reduce_kernel<<<MM * 2048 / 8 / 256, 256, 0, stream>>>(attb, hs_b, MM * 2048 / 8);
  gemm_bt<1><<<dim3(32, 16), 256, 0, stream>>>(attb, Wo_b, nullptr, nullptr, d_out);
}

// Round 6
// 389.358 us; speedup vs baseline: 1.2495x; 1.2495x over previous
//
#include <hip/hip_runtime.h>
#include <hip/hip_bf16.h>

typedef __attribute__((ext_vector_type(8))) short v8s;   // 8 x bf16 (4 VGPRs)
typedef __attribute__((ext_vector_type(4))) float v4f;   // MFMA accum

#define GL16(g, l) __builtin_amdgcn_global_load_lds(                    \
    (const __attribute__((address_space(1))) void*)(g),                 \
    (__attribute__((address_space(3))) void*)(l), 16, 0, 0)

static constexpr int BB = 2, SS = 2048, HIDC = 2048, NH = 16, NKV = 4, DD = 128;
static constexpr int MM = BB * SS;        // 4096 rows
static constexpr int LDQKV = 3072;        // q(2048) | k(512) | v(512)
static constexpr int NCHUNK = 32;         // S / SPLIT
static constexpr int NCG = 2;             // chunk groups (parallel split)
static constexpr int CPG = NCHUNK / NCG;  // chunks per group = 16
#define SCALE_F 0.08838834764831845f

__device__ __forceinline__ unsigned short bf16b(float x) {
  unsigned u = __float_as_uint(x);
  u += 0x7fffu + ((u >> 16) & 1u);        // RTNE
  return (unsigned short)(u >> 16);
}
__device__ __forceinline__ unsigned pk2(float lo, float hi) {
  return (unsigned)bf16b(lo) | ((unsigned)bf16b(hi) << 16);
}
__device__ __forceinline__ float bf2f(unsigned short u) {
  return __uint_as_float((unsigned)u << 16);
}

// ---------------- fp32 -> bf16 cast ----------------
__global__ __launch_bounds__(256) void cast_kernel(
    const float* __restrict__ in, unsigned short* __restrict__ out, int n4) {
  int i = blockIdx.x * blockDim.x + threadIdx.x;
  if (i >= n4) return;
  v4f v = reinterpret_cast<const v4f*>(in)[i];
  ushort4 o;
  o.x = bf16b(v[0]); o.y = bf16b(v[1]); o.z = bf16b(v[2]); o.w = bf16b(v[3]);
  reinterpret_cast<ushort4*>(out)[i] = o;
}

// ---------------- NT GEMM, m97 structure: 128x128 tile, BK=32 ----------------
// C[m][n] = sum_k A[m][k] * B[n][k].  MODE 0: fused QKV -> bf16 qkv buffer
// (ldc=3072, weight selected per n-block). MODE 1: fp32 C (out projection).
template <int MODE>
__global__ __launch_bounds__(256) void gemm_bt(
    const unsigned short* __restrict__ A, const unsigned short* __restrict__ W0,
    const unsigned short* __restrict__ W1, const unsigned short* __restrict__ W2,
    void* __restrict__ Cout) {
  __shared__ __align__(16) unsigned short As[128 * 32];
  __shared__ __align__(16) unsigned short Bs[128 * 32];
  const int K = HIDC;
  int mb = blockIdx.x, nb = blockIdx.y;
  int tid = threadIdx.x, wid = tid >> 6, lane = tid & 63;
  int l15 = lane & 15, g = lane >> 4;
  const unsigned short* Bsel;
  int nloc0, ldc;
  if (MODE == 0) {
    if (nb < 16)      { Bsel = W0; nloc0 = nb * 128; }
    else if (nb < 20) { Bsel = W1; nloc0 = (nb - 16) * 128; }
    else              { Bsel = W2; nloc0 = (nb - 20) * 128; }
    ldc = LDQKV;
  } else {
    Bsel = W0; nloc0 = nb * 128; ldc = 2048;
  }
  int wr = wid >> 1, wc = wid & 1;
  v4f acc[4][4] = {};

  for (int kt = 0; kt < K / 32; ++kt) {
    // stage A,B tiles: 512 chunks of 16B each; swizzle chunk' = chunk ^ ((row>>1)&3)
#pragma unroll
    for (int i = 0; i < 2; ++i) {
      int ci = (i * 4 + wid) * 64 + lane;          // 0..511
      int row = ci >> 2, ch = ci & 3;
      int cg = ch ^ ((row >> 1) & 3);
      const unsigned short* ga = A + (size_t)(mb * 128 + row) * K + kt * 32 + cg * 8;
      GL16(ga, (char*)As + (size_t)(i * 4 + wid) * 1024);
      const unsigned short* gb = Bsel + (size_t)(nloc0 + row) * K + kt * 32 + cg * 8;
      GL16(gb, (char*)Bs + (size_t)(i * 4 + wid) * 1024);
    }
    __syncthreads();
    v8s af[4], bfr[4];
#pragma unroll
    for (int mi = 0; mi < 4; ++mi) {
      int row = wr * 64 + mi * 16 + l15;
      int ch = g ^ ((row >> 1) & 3);
      af[mi] = *reinterpret_cast<const v8s*>(&As[row * 32 + ch * 8]);
    }
#pragma unroll
    for (int ni = 0; ni < 4; ++ni) {
      int row = wc * 64 + ni * 16 + l15;
      int ch = g ^ ((row >> 1) & 3);
      bfr[ni] = *reinterpret_cast<const v8s*>(&Bs[row * 32 + ch * 8]);
    }
#pragma unroll
    for (int mi = 0; mi < 4; ++mi)
#pragma unroll
      for (int ni = 0; ni < 4; ++ni)
        acc[mi][ni] = __builtin_amdgcn_mfma_f32_16x16x32_bf16(
            af[mi], bfr[ni], acc[mi][ni], 0, 0, 0);
    __syncthreads();
  }

  // epilogue: C/D layout col = lane&15, row = (lane>>4)*4 + i
  int cbase = nb * 128;
  if (MODE == 0) {
    unsigned short* C = (unsigned short*)Cout;
#pragma unroll
    for (int mi = 0; mi < 4; ++mi)
#pragma unroll
      for (int ni = 0; ni < 4; ++ni)
#pragma unroll
        for (int i = 0; i < 4; ++i) {
          int r = mb * 128 + wr * 64 + mi * 16 + g * 4 + i;
          int cc = cbase + wc * 64 + ni * 16 + l15;
          C[(size_t)r * ldc + cc] = bf16b(acc[mi][ni][i]);
        }
  } else {
    float* C = (float*)Cout;
#pragma unroll
    for (int mi = 0; mi < 4; ++mi)
#pragma unroll
      for (int ni = 0; ni < 4; ++ni)
#pragma unroll
        for (int i = 0; i < 4; ++i) {
          int r = mb * 128 + wr * 64 + mi * 16 + g * 4 + i;
          int cc = cbase + wc * 64 + ni * 16 + l15;
          C[(size_t)r * ldc + cc] = acc[mi][ni][i];
        }
  }
}

// ---------------- V transpose: qkv v-cols -> VT[b][kh][d][s] ----------------
__global__ __launch_bounds__(256) void transpose_v(
    const unsigned short* __restrict__ qkv, unsigned short* __restrict__ VT) {
  __shared__ __align__(16) unsigned short t_lds[64 * 72];
  int blk = blockIdx.x;              // 512 = 2b * 4kh * 2dt * 32st
  int st = blk & 31;
  int dt = (blk >> 5) & 1;
  int bkh = blk >> 6;                // b*4 + kh
  int b = bkh >> 2, kh = bkh & 3;
  int tid = threadIdx.x;
  int si = tid >> 2, c8 = (tid & 3) * 16;
  const unsigned short* src =
      qkv + (size_t)(b * SS + st * 64 + si) * LDQKV + 2560 + kh * 128 + dt * 64 + c8;
  *reinterpret_cast<v8s*>(&t_lds[si * 72 + c8]) = *reinterpret_cast<const v8s*>(src);
  *reinterpret_cast<v8s*>(&t_lds[si * 72 + c8 + 8]) = *reinterpret_cast<const v8s*>(src + 8);
  __syncthreads();
  int dl = tid >> 2, s0 = (tid & 3) * 16;
  union { unsigned short u[16]; v8s v[2]; } tt;
#pragma unroll
  for (int j = 0; j < 16; ++j) tt.u[j] = t_lds[(s0 + j) * 72 + dl];
  unsigned short* dst = VT + (size_t)(bkh * 128 + dt * 64 + dl) * SS + st * 64 + s0;
  *reinterpret_cast<v8s*>(dst) = tt.v[0];
  *reinterpret_cast<v8s*>(dst + 8) = tt.v[1];
}

// ---------------- fused chunked attention (double-buffered pipeline) ----------------
// Grid 1024: logical = cg(1)|b(1)|qt(4)|h(4)  (cg in TOP bit: each XCD holds all
// 16 heads x contiguous q-tiles -> round-1's proven L2 locality).
// 2-phase pipeline (T3 minimum recipe): stage chunk c+1 into buf^1 while
// computing chunk c from buf; one vmcnt(0)+s_barrier per chunk.
__global__ __launch_bounds__(256) void attn_kernel(
    const unsigned short* __restrict__ qkv, const unsigned short* __restrict__ VT,
    const float* __restrict__ mask, unsigned short* __restrict__ part0,
    unsigned short* __restrict__ part1) {
  __shared__ __align__(16) unsigned short K_lds[2][64 * 128];   // [key][d] swizzled
  __shared__ __align__(16) unsigned short V_lds[2][128 * 64];   // [d][key] swizzled
  int wg = blockIdx.x;
  int logical = (wg & 7) * 128 + (wg >> 3);   // contiguous 128-chunk per XCD
  int h = logical & 15;
  int qt = (logical >> 4) & 15;
  int b = (logical >> 8) & 1;
  int cg = logical >> 9;
  int kh = h >> 2;
  int tid = threadIdx.x, wid = tid >> 6, lane = tid & 63;
  int l15 = lane & 15, g = lane >> 4;
  int qr0 = qt * 128 + wid * 32;

  // Q fragments in registers: B-operand of swapped QK^T (Q rows, K-contig)
  v8s qf[2][4];
#pragma unroll
  for (int nf = 0; nf < 2; ++nf)
#pragma unroll
    for (int ks = 0; ks < 4; ++ks) {
      const unsigned short* src =
          qkv + (size_t)(b * SS + qr0 + nf * 16 + l15) * LDQKV + h * 128 + ks * 32 + g * 8;
      qf[nf][ks] = *reinterpret_cast<const v8s*>(src);
    }

  v4f oacc[8][2] = {};   // O^T: [d-frag][q-frag]

  const size_t krowbase = (size_t)b * SS * LDQKV + 2048 + kh * 128;
  const unsigned short* vtbase = VT + (size_t)(b * 4 + kh) * 128 * SS;
  const int c0 = cg * CPG;

  // stage K (64x128, 16 chunks/row) and VT (128x64, 8 chunks/row) for chunk c,
  // source pre-swizzled: stored chunk' holds global chunk (chunk' ^ (row&7))
  auto stage = [&](int bufi, int c) {
#pragma unroll
    for (int i = 0; i < 4; ++i) {
      int ci = (i * 4 + wid) * 64 + lane;    // 0..1023
      {
        int row = ci >> 4, ch = ci & 15;
        int cgx = ch ^ (row & 7);
        const unsigned short* gk =
            qkv + krowbase + (size_t)(c * 64 + row) * LDQKV + cgx * 8;
        GL16(gk, (char*)(&K_lds[bufi][0]) + (size_t)(i * 4 + wid) * 1024);
      }
      {
        int row = ci >> 3, ch = ci & 7;
        int cgx = ch ^ (row & 7);
        const unsigned short* gv = vtbase + (size_t)row * SS + c * 64 + cgx * 8;
        GL16(gv, (char*)(&V_lds[bufi][0]) + (size_t)(i * 4 + wid) * 1024);
      }
    }
  };

  // prologue: fill buf 0
  stage(0, c0);
  asm volatile("s_waitcnt vmcnt(0)" ::: "memory");
  __builtin_amdgcn_s_barrier();

  int cur = 0;
  for (int cc = 0; cc < CPG; ++cc) {
    int c = c0 + cc;
    // issue next chunk's loads into the other buffer (overlaps with compute below)
    if (cc + 1 < CPG) stage(cur ^ 1, c + 1);

    const unsigned short* Kc = &K_lds[cur][0];
    const unsigned short* Vc = &V_lds[cur][0];

    // S^T = K * Q^T  (M=64 keys, N=32 q, K-dim = 128 d)
    v4f sc[4][2] = {};
#pragma unroll
    for (int ks = 0; ks < 4; ++ks) {
      v8s kf[4];
#pragma unroll
      for (int mf = 0; mf < 4; ++mf) {
        int row = mf * 16 + l15;
        int ch = (4 * ks + g) ^ (row & 7);
        kf[mf] = *reinterpret_cast<const v8s*>(&Kc[row * 128 + ch * 8]);
      }
#pragma unroll
      for (int mf = 0; mf < 4; ++mf)
#pragma unroll
        for (int nf = 0; nf < 2; ++nf)
          sc[mf][nf] = __builtin_amdgcn_mfma_f32_16x16x32_bf16(
              kf[mf], qf[nf][ks], sc[mf][nf], 0, 0, 0);
    }

    // scale + mask: value(key = c*64 + mf*16 + g*4 + i, q = qr0 + nf*16 + l15)
#pragma unroll
    for (int mf = 0; mf < 4; ++mf)
#pragma unroll
      for (int nf = 0; nf < 2; ++nf) {
        int q = qr0 + nf * 16 + l15;
        v4f mv = *reinterpret_cast<const v4f*>(
            mask + (size_t)(b * SS + q) * SS + c * 64 + mf * 16 + g * 4);
#pragma unroll
        for (int i = 0; i < 4; ++i)
          sc[mf][nf][i] = sc[mf][nf][i] * SCALE_F + mv[i];
      }

    // chunk-local softmax over 64 keys per q (in-lane 16 + shfl_xor 16,32)
    unsigned wA[4][2], wB[4][2];
#pragma unroll
    for (int nf = 0; nf < 2; ++nf) {
      float m = -1e30f;
#pragma unroll
      for (int mf = 0; mf < 4; ++mf)
#pragma unroll
        for (int i = 0; i < 4; ++i) m = fmaxf(m, sc[mf][nf][i]);
      m = fmaxf(m, __shfl_xor(m, 16));
      m = fmaxf(m, __shfl_xor(m, 32));
      float s = 0.f;
#pragma unroll
      for (int mf = 0; mf < 4; ++mf)
#pragma unroll
        for (int i = 0; i < 4; ++i) {
          float p = __expf(sc[mf][nf][i] - m);
          sc[mf][nf][i] = p;
          s += p;
        }
      s += __shfl_xor(s, 16);
      s += __shfl_xor(s, 32);
      float r = 1.f / s;
#pragma unroll
      for (int mf = 0; mf < 4; ++mf) {
        wA[mf][nf] = pk2(sc[mf][nf][0] * r, sc[mf][nf][1] * r);
        wB[mf][nf] = pk2(sc[mf][nf][2] * r, sc[mf][nf][3] * r);
      }
    }

    // O^T += V^T * P^T : build P^T B-frags in-register (group shuffles)
    int src0 = ((lane >> 4) & 1) * 32 + l15;
    int src1 = src0 + 16;
    bool hi = lane >= 32;    // selects frag m = 2t + (g>>1)
#pragma unroll
    for (int t = 0; t < 2; ++t) {
      v8s vf[8];
#pragma unroll
      for (int mf = 0; mf < 8; ++mf) {
        int row = mf * 16 + l15;
        int ch = (4 * t + g) ^ (row & 7);
        vf[mf] = *reinterpret_cast<const v8s*>(&Vc[row * 64 + ch * 8]);
      }
#pragma unroll
      for (int nf = 0; nf < 2; ++nf) {
        int m0 = 2 * t, m1 = 2 * t + 1;
        unsigned aA0 = __shfl(wA[m0][nf], src0);
        unsigned aA1 = __shfl(wA[m1][nf], src0);
        unsigned aB0 = __shfl(wB[m0][nf], src0);
        unsigned aB1 = __shfl(wB[m1][nf], src0);
        unsigned cA0 = __shfl(wA[m0][nf], src1);
        unsigned cA1 = __shfl(wA[m1][nf], src1);
        unsigned cB0 = __shfl(wB[m0][nf], src1);
        unsigned cB1 = __shfl(wB[m1][nf], src1);
        union { unsigned u[4]; v8s s; } pb;
        pb.u[0] = hi ? aA1 : aA0;
        pb.u[1] = hi ? aB1 : aB0;
        pb.u[2] = hi ? cA1 : cA0;
        pb.u[3] = hi ? cB1 : cB0;
#pragma unroll
        for (int mf = 0; mf < 8; ++mf)
          oacc[mf][nf] = __builtin_amdgcn_mfma_f32_16x16x32_bf16(
              vf[mf], pb.s, oacc[mf][nf], 0, 0, 0);
      }
    }

    // all ds_reads of buf[cur] were consumed above (lgkm-waited before MFMA use);
    // wait for next-chunk DMA, then barrier -> buf[cur^1] ready, buf[cur] free.
    asm volatile("s_waitcnt vmcnt(0)" ::: "memory");
    __builtin_amdgcn_s_barrier();
    cur ^= 1;
  }

  // epilogue: raw partial sum (no /32 here), bf16 -> part0 (cg=0) or part1 (cg=1)
  unsigned short* pslab = cg ? part1 : part0;
#pragma unroll
  for (int nf = 0; nf < 2; ++nf) {
    int q = qr0 + nf * 16 + l15;
#pragma unroll
    for (int mf = 0; mf < 8; ++mf) {
      ushort4 o;
      o.x = bf16b(oacc[mf][nf][0]);
      o.y = bf16b(oacc[mf][nf][1]);
      o.z = bf16b(oacc[mf][nf][2]);
      o.w = bf16b(oacc[mf][nf][3]);
      *reinterpret_cast<ushort4*>(
          pslab + (size_t)(b * SS + q) * 2048 + h * 128 + mf * 16 + g * 4) = o;
    }
  }
}

// ---------------- partial reduce (in place): p0 = (p0 + p1) / 32 ----------------
__global__ __launch_bounds__(256) void reduce_kernel(
    unsigned short* __restrict__ p0, const unsigned short* __restrict__ p1, int n8) {
  int i = blockIdx.x * blockDim.x + threadIdx.x;
  if (i >= n8) return;
  v8s a = reinterpret_cast<const v8s*>(p0)[i];
  v8s bb = reinterpret_cast<const v8s*>(p1)[i];
  const float inv = 1.f / 32.f;
  union { unsigned short u[8]; v8s v; } o;
#pragma unroll
  for (int j = 0; j < 8; ++j)
    o.u[j] = bf16b((bf2f((unsigned short)a[j]) + bf2f((unsigned short)bb[j])) * inv);
  reinterpret_cast<v8s*>(p0)[i] = o.v;
}

// ---------------- host ----------------
extern "C" void kernel_launch(void* const* d_in, const int* in_sizes, int n_in,
                              void* d_out, int out_size, void* d_ws, size_t ws_size,
                              hipStream_t stream) {
  const float* hs   = (const float*)d_in[0];
  const float* mask = (const float*)d_in[1];
  const float* Wq   = (const float*)d_in[2];
  const float* Wk   = (const float*)d_in[3];
  const float* Wv   = (const float*)d_in[4];
  const float* Wo   = (const float*)d_in[5];

  char* ws = (char*)d_ws;
  size_t off = 0;
  auto alloc = [&](size_t bytes) {
    void* p = ws + off;
    off += (bytes + 255) & ~(size_t)255;
    return p;
  };
  // Buffer plan (84 MB total — identical footprint to the known-good round 1):
  //   hs_b: QKV-GEMM input A; DEAD after gemm<0> -> reused as partial slab 1.
  //   attb: partial slab 0, reduced in place, then out-GEMM input A.
  unsigned short* hs_b = (unsigned short*)alloc((size_t)MM * HIDC * 2);
  unsigned short* Wq_b = (unsigned short*)alloc((size_t)2048 * 2048 * 2);
  unsigned short* Wk_b = (unsigned short*)alloc((size_t)512 * 2048 * 2);
  unsigned short* Wv_b = (unsigned short*)alloc((size_t)512 * 2048 * 2);
  unsigned short* Wo_b = (unsigned short*)alloc((size_t)2048 * 2048 * 2);
  unsigned short* qkvb = (unsigned short*)alloc((size_t)MM * LDQKV * 2);
  unsigned short* VTb  = (unsigned short*)alloc((size_t)8 * 128 * SS * 2);
  unsigned short* attb = (unsigned short*)alloc((size_t)MM * 2048 * 2);
  (void)ws_size; (void)in_sizes; (void)n_in; (void)out_size;

  cast_kernel<<<MM * HIDC / 1024, 256, 0, stream>>>(hs, hs_b, MM * HIDC / 4);
  cast_kernel<<<2048 * 2048 / 1024, 256, 0, stream>>>(Wq, Wq_b, 2048 * 2048 / 4);
  cast_kernel<<<512 * 2048 / 1024, 256, 0, stream>>>(Wk, Wk_b, 512 * 2048 / 4);
  cast_kernel<<<512 * 2048 / 1024, 256, 0, stream>>>(Wv, Wv_b, 512 * 2048 / 4);
  cast_kernel<<<2048 * 2048 / 1024, 256, 0, stream>>>(Wo, Wo_b, 2048 * 2048 / 4);

  gemm_bt<0><<<dim3(32, 24), 256, 0, stream>>>(hs_b, Wq_b, Wk_b, Wv_b, (void*)qkvb);
  transpose_v<<<512, 256, 0, stream>>>(qkvb, VTb);
  attn_kernel<<<1024, 256, 0, stream>>>(qkvb, VTb, mask, attb, hs_b);
  reduce_kernel<<<MM * 2048 / 8 / 256, 256, 0, stream>>>(attb, hs_b, MM * 2048 / 8);
  gemm_bt<1><<<dim3(32, 16), 256, 0, stream>>>(attb, Wo_b, nullptr, nullptr, d_out);
}